// Round 9
// baseline (790.079 us; speedup 1.0000x reference)
//
#include <hip/hip_runtime.h>

// GNN: 2-layer edge-coloured conv on MI355X.
// Round 9 (= round 8 resubmit after infra failure): single-barrier mega-LDS
// gather. All 8 colour slabs staged at once (64KB LDS), 8 independent walks
// per thread with hoisted oc loads, ONE __syncthreads, then uninterrupted
// MFMA over all colours + self.
// gemm1: 32-row blocks (grid 1563); gemm2: 16-row blocks (grid 3125).

#define NN 50000
#define EE 800000
#define DD 128
#define HH 256
#define CC 8
#define K1 1152   // C*D + D
#define K2 2304   // C*H + H

typedef unsigned short u16;
typedef __attribute__((ext_vector_type(8))) short s16x8;
typedef __attribute__((ext_vector_type(4))) float f32x4;

__device__ __forceinline__ float bf2f(short u) {
  return __uint_as_float(((unsigned)(u16)u) << 16);
}
__device__ __forceinline__ u16 f2bf(float f) {
  unsigned u = __float_as_uint(f);
  u = (u + 0x7FFFu + ((u >> 16) & 1u)) >> 16;   // RNE
  return (u16)u;
}

// One thread aggregates a 32B (16-elt) chunk of one CSR segment into s[16].
__device__ __forceinline__ void gather32B(const u16* __restrict__ src, int stride,
                                          const int* __restrict__ ssrc,
                                          int st, int cn, int eoff, float* s) {
#pragma unroll
  for (int q = 0; q < 16; q++) s[q] = 0.f;
  for (int j = 0; j < cn; j += 4) {
    int idx[4];
#pragma unroll
    for (int t = 0; t < 4; t++) idx[t] = (j + t < cn) ? ssrc[st + j + t] : -1;
#pragma unroll
    for (int t = 0; t < 4; t++) {
      if (idx[t] >= 0) {
        const u16* pp = src + (size_t)idx[t] * stride + eoff;
        s16x8 lo = *(const s16x8*)pp;
        s16x8 hi = *(const s16x8*)(pp + 8);
#pragma unroll
        for (int q = 0; q < 8; q++) s[q] += bf2f(lo[q]);
#pragma unroll
        for (int q = 0; q < 8; q++) s[q + 8] += bf2f(hi[q]);
      }
    }
  }
}

__device__ __forceinline__ void lds_put32(char* As, unsigned base, unsigned swz,
                                          const float* s) {
  s16x8 lo, hi;
#pragma unroll
  for (int q = 0; q < 8; q++) lo[q] = (short)f2bf(s[q]);
#pragma unroll
  for (int q = 0; q < 8; q++) hi[q] = (short)f2bf(s[q + 8]);
  *(s16x8*)(As + (base ^ swz)) = lo;
  *(s16x8*)(As + ((base + 16) ^ swz)) = hi;
}

// ---------------- prep ----------------

__global__ void k_castx(const float* __restrict__ x, u16* __restrict__ xb) {
  int i = blockIdx.x * 256 + threadIdx.x;
  if (i < NN * DD) xb[i] = f2bf(x[i]);
}

__global__ void k_wt1(const float* __restrict__ Wc1, const float* __restrict__ Ws1,
                      u16* __restrict__ Wt1) {
  int i = blockIdx.x * 256 + threadIdx.x;
  if (i >= HH * K1) return;
  int o = i / K1, k = i - o * K1;
  float v = (k < CC * DD) ? Wc1[(k >> 7) * (HH * DD) + o * DD + (k & 127)]
                          : Ws1[o * DD + (k - CC * DD)];
  Wt1[i] = f2bf(v);
}

__global__ void k_wt2(const float* __restrict__ Wc2, const float* __restrict__ Ws2,
                      u16* __restrict__ Wt2) {
  int i = blockIdx.x * 256 + threadIdx.x;
  if (i >= DD * K2) return;
  int o = i / K2, k = i - o * K2;
  float v = (k < CC * HH) ? Wc2[(k >> 8) * (DD * HH) + o * HH + (k & 255)]
                          : Ws2[o * HH + (k - CC * HH)];
  Wt2[i] = f2bf(v);
}

// ---------------- CSR build over seg = c*N + dst ----------------

__global__ void k_hist(const int* __restrict__ ei, const int* __restrict__ ec,
                       int* __restrict__ counts) {
  int e = blockIdx.x * 256 + threadIdx.x;
  if (e < EE) {
    int dst = ei[EE + e];
    int c = ec[e];
    atomicAdd(&counts[c * NN + dst], 1);
  }
}

__global__ void k_offsets(const int* __restrict__ counts, int2* __restrict__ oc,
                          int* __restrict__ cursor, int* __restrict__ gcount) {
  __shared__ int lds[256];
  __shared__ int basesh;
  int tid = threadIdx.x;
  int i = blockIdx.x * 256 + tid;
  int c = (i < CC * NN) ? counts[i] : 0;
  lds[tid] = c;
  __syncthreads();
  int v = c;
  for (int s = 1; s < 256; s <<= 1) {
    int t = (tid >= s) ? lds[tid - s] : 0;
    __syncthreads();
    v += t;
    lds[tid] = v;
    __syncthreads();
  }
  if (tid == 255) basesh = atomicAdd(gcount, v);
  __syncthreads();
  int excl = basesh + v - c;
  if (i < CC * NN) {
    oc[i] = make_int2(excl, c);
    cursor[i] = excl;
  }
}

__global__ void k_fill(const int* __restrict__ ei, const int* __restrict__ ec,
                       int* __restrict__ cursor, int* __restrict__ ssrc) {
  int e = blockIdx.x * 256 + threadIdx.x;
  if (e < EE) {
    int src = ei[e];
    int dst = ei[EE + e];
    int seg = ec[e] * NN + dst;
    int slot = atomicAdd(&cursor[seg], 1);
    ssrc[slot] = src;
  }
}

// ---------------- fused single-barrier gather + GEMM ----------------
// A-frag: row=lane&15, k=8*(lane>>4)+j. B-frag from Wt[o][k].
// C/D: col=lane&15, row=(lane>>4)*4+reg. LDS swizzle: byte ^= (row&7)<<4.

__global__ void __launch_bounds__(256) k_gemm1(
    const u16* __restrict__ xb, const u16* __restrict__ Wt,
    const float* __restrict__ b1,
    const int2* __restrict__ oc, const int* __restrict__ ssrc,
    u16* __restrict__ hb) {
  __shared__ char As[CC * 8192];          // 8 slabs x (32 rows x 256B) = 64KB
  int tid = threadIdx.x;
  int w = tid >> 6, lane = tid & 63;
  int rs = lane & 15, kg = lane >> 4;
  int rt = w >> 1, ch = w & 1;
  int r0 = blockIdx.x * 32;
  int rowl = rt * 16 + rs;
  unsigned swzr = (rowl & 7) << 4;
  int rowL = min(r0 + rowl, NN - 1);
  // gather: thread = (seg, 32B-chunk), walks all 8 colours
  int gseg = tid >> 3, gchunk = tid & 7;
  int grow = r0 + gseg;
  unsigned gbase = gseg * 256 + gchunk * 32;
  unsigned gswz = (gseg & 7) << 4;

  int2 se[CC];
#pragma unroll
  for (int c = 0; c < CC; ++c)
    se[c] = (grow < NN) ? oc[c * NN + grow] : make_int2(0, 0);

#pragma unroll
  for (int c = 0; c < CC; ++c) {
    float s[16];
    gather32B(xb, DD, ssrc, se[c].x, se[c].y, gchunk * 16, s);
    lds_put32(As + c * 8192, gbase, gswz, s);
  }
  __syncthreads();

  f32x4 acc[8];
#pragma unroll
  for (int i = 0; i < 8; i++)
#pragma unroll
    for (int q = 0; q < 4; q++) acc[i][q] = 0.f;

  for (int c = 0; c < CC; ++c) {
#pragma unroll
    for (int kk = 0; kk < 4; ++kk) {
      unsigned L = rowl * 256 + kk * 64 + kg * 16;
      s16x8 af = *(const s16x8*)(As + c * 8192 + (L ^ swzr));
      int k0 = c * 128 + kk * 32;
#pragma unroll
      for (int fc = 0; fc < 8; ++fc) {
        int col = ch * 128 + fc * 16 + rs;
        s16x8 bfr = *(const s16x8*)(Wt + col * K1 + k0 + kg * 8);
        acc[fc] = __builtin_amdgcn_mfma_f32_16x16x32_bf16(af, bfr, acc[fc], 0, 0, 0);
      }
    }
  }
  // self block (A = x, direct from global)
#pragma unroll
  for (int kk = 0; kk < 4; ++kk) {
    s16x8 af = *(const s16x8*)(xb + rowL * DD + kk * 32 + kg * 8);
    int k0 = CC * DD + kk * 32;
#pragma unroll
    for (int fc = 0; fc < 8; ++fc) {
      int col = ch * 128 + fc * 16 + rs;
      s16x8 bfr = *(const s16x8*)(Wt + col * K1 + k0 + kg * 8);
      acc[fc] = __builtin_amdgcn_mfma_f32_16x16x32_bf16(af, bfr, acc[fc], 0, 0, 0);
    }
  }
#pragma unroll
  for (int fc = 0; fc < 8; ++fc) {
    int col = ch * 128 + fc * 16 + rs;
    float bias = b1[col];
#pragma unroll
    for (int q = 0; q < 4; ++q) {
      float v = acc[fc][q] + bias;
      if (v < 0.f) v = 0.f;
      int rr = r0 + rt * 16 + kg * 4 + q;
      if (rr < NN) hb[rr * HH + col] = f2bf(v);
    }
  }
}

__global__ void __launch_bounds__(256) k_gemm2(
    const u16* __restrict__ hb, const u16* __restrict__ Wt,
    const float* __restrict__ b2,
    const int2* __restrict__ oc, const int* __restrict__ ssrc,
    float* __restrict__ out) {
  __shared__ char As[CC * 8192];          // 8 slabs x (16 rows x 512B) = 64KB
  int tid = threadIdx.x;
  int w = tid >> 6, lane = tid & 63;
  int rs = lane & 15, kg = lane >> 4;
  int ch = w;                             // wave owns 32 cols of 128
  int r0 = blockIdx.x * 16;               // 3125*16 = 50000 exact
  int rowl = rs;
  unsigned swzr = (rowl & 7) << 4;
  int rowL = r0 + rowl;
  // gather: thread = (seg, 32B-chunk), walks all 8 colours
  int gseg = tid >> 4, gchunk = tid & 15;
  int grow = r0 + gseg;
  unsigned gbase = gseg * 512 + gchunk * 32;
  unsigned gswz = (gseg & 7) << 4;

  int2 se[CC];
#pragma unroll
  for (int c = 0; c < CC; ++c)
    se[c] = oc[c * NN + grow];

#pragma unroll
  for (int c = 0; c < CC; ++c) {
    float s[16];
    gather32B(hb, HH, ssrc, se[c].x, se[c].y, gchunk * 16, s);
    lds_put32(As + c * 8192, gbase, gswz, s);
  }
  __syncthreads();

  f32x4 acc[2];
#pragma unroll
  for (int i = 0; i < 2; i++)
#pragma unroll
    for (int q = 0; q < 4; q++) acc[i][q] = 0.f;

  for (int c = 0; c < CC; ++c) {
#pragma unroll
    for (int kk = 0; kk < 8; ++kk) {
      unsigned L = rowl * 512 + kk * 64 + kg * 16;
      s16x8 af = *(const s16x8*)(As + c * 8192 + (L ^ swzr));
      int k0 = c * 256 + kk * 32;
#pragma unroll
      for (int fc = 0; fc < 2; ++fc) {
        int col = ch * 32 + fc * 16 + rs;
        s16x8 bfr = *(const s16x8*)(Wt + col * K2 + k0 + kg * 8);
        acc[fc] = __builtin_amdgcn_mfma_f32_16x16x32_bf16(af, bfr, acc[fc], 0, 0, 0);
      }
    }
  }
  // self block (A = h, direct from global)
#pragma unroll
  for (int kk = 0; kk < 8; ++kk) {
    s16x8 af = *(const s16x8*)(hb + rowL * HH + kk * 32 + kg * 8);
    int k0 = CC * HH + kk * 32;
#pragma unroll
    for (int fc = 0; fc < 2; ++fc) {
      int col = ch * 32 + fc * 16 + rs;
      s16x8 bfr = *(const s16x8*)(Wt + col * K2 + k0 + kg * 8);
      acc[fc] = __builtin_amdgcn_mfma_f32_16x16x32_bf16(af, bfr, acc[fc], 0, 0, 0);
    }
  }
#pragma unroll
  for (int fc = 0; fc < 2; ++fc) {
    int col = ch * 32 + fc * 16 + rs;
    float bias = b2[col];
#pragma unroll
    for (int q = 0; q < 4; ++q) {
      float v = acc[fc][q] + bias;
      int rr = r0 + kg * 4 + q;
      out[rr * DD + col] = 1.f / (1.f + expf(10.f - v));
    }
  }
}

// ---------------- launch ----------------

extern "C" void kernel_launch(void* const* d_in, const int* in_sizes, int n_in,
                              void* d_out, int out_size, void* d_ws, size_t ws_size,
                              hipStream_t stream) {
  const float* x   = (const float*)d_in[0];
  const int*   ei  = (const int*)d_in[1];
  const int*   ec  = (const int*)d_in[2];
  const float* Ws1 = (const float*)d_in[3];
  const float* b1  = (const float*)d_in[4];
  const float* Ws2 = (const float*)d_in[5];
  const float* b2  = (const float*)d_in[6];
  const float* Wc1 = (const float*)d_in[7];
  const float* Wc2 = (const float*)d_in[8];
  float* out = (float*)d_out;

  char* p = (char*)d_ws;
  u16*  xb     = (u16*)p;  p += 12800000;   // x bf16 [N,128]
  u16*  Wt1    = (u16*)p;  p += 589824;     // [256,1152] bf16
  u16*  Wt2    = (u16*)p;  p += 589824;     // [128,2304] bf16
  int*  counts = (int*)p;  p += 1600000;    // [C*N]
  int*  gcount = (int*)p;  p += 256;
  int2* oc     = (int2*)p; p += 3200000;    // [C*N] {off, cnt}
  int*  cursor = (int*)p;  p += 1600000;    // [C*N]
  int*  ssrc   = (int*)p;  p += 3200000;    // [E]
  u16*  hb     = (u16*)p;  p += 25600000;   // h bf16 [N,256]

  hipMemsetAsync(counts, 0, 1600000 + 256, stream);  // counts + gcount

  k_castx<<<25000, 256, 0, stream>>>(x, xb);
  k_wt1<<<1152, 256, 0, stream>>>(Wc1, Ws1, Wt1);
  k_wt2<<<1152, 256, 0, stream>>>(Wc2, Ws2, Wt2);

  k_hist<<<3125, 256, 0, stream>>>(ei, ec, counts);
  k_offsets<<<1563, 256, 0, stream>>>(counts, oc, cursor, gcount);
  k_fill<<<3125, 256, 0, stream>>>(ei, ec, cursor, ssrc);

  k_gemm1<<<1563, 256, 0, stream>>>(xb, Wt1, b1, oc, ssrc, hb);
  k_gemm2<<<3125, 256, 0, stream>>>(hb, Wt2, b2, oc, ssrc, out);
}

// Round 12
// 725.079 us; speedup vs baseline: 1.0896x; 1.0896x over previous
//
#include <hip/hip_runtime.h>

// GNN: 2-layer edge-coloured conv on MI355X.
// Round 12 (= round 10 resubmit; infra failures r10/r11): decoupled pipeline.
// Layer1: pure-gather agg1 -> dense GEMM. Layer2: multiply-first
// g2 = h@[Wc2 cat Ws2]^T (dense GEMM), then pure gather-sum-sigmoid
// (256B/edge instead of 512B). Gather kernels have no LDS/no barriers/low
// VGPR -> max occupancy -> BW-bound not latency-bound.

#define NN 50000
#define EE 800000
#define DD 128
#define HH 256
#define CC 8
#define K1 1152   // C*D + D

typedef unsigned short u16;
typedef __attribute__((ext_vector_type(8))) short s16x8;
typedef __attribute__((ext_vector_type(4))) float f32x4;

__device__ __forceinline__ float bf2f(short u) {
  return __uint_as_float(((unsigned)(u16)u) << 16);
}
__device__ __forceinline__ u16 f2bf(float f) {
  unsigned u = __float_as_uint(f);
  u = (u + 0x7FFFu + ((u >> 16) & 1u)) >> 16;   // RNE
  return (u16)u;
}

// ---------------- prep ----------------

__global__ void k_castx(const float* __restrict__ x, u16* __restrict__ xb) {
  int i = blockIdx.x * 256 + threadIdx.x;
  if (i < NN * DD) xb[i] = f2bf(x[i]);
}

// Wt1[o][k], o<256, k = c*128+f (c<8) | 1024+f (self)
__global__ void k_wt1(const float* __restrict__ Wc1, const float* __restrict__ Ws1,
                      u16* __restrict__ Wt1) {
  int i = blockIdx.x * 256 + threadIdx.x;
  if (i >= HH * K1) return;
  int o = i / K1, k = i - o * K1;
  float v = (k < CC * DD) ? Wc1[(k >> 7) * (HH * DD) + o * DD + (k & 127)]
                          : Ws1[o * DD + (k - CC * DD)];
  Wt1[i] = f2bf(v);
}

// Wt2g[oc][k], oc = c*128+o (c<8) | 1024+o (self), k<256
__global__ void k_wt2g(const float* __restrict__ Wc2, const float* __restrict__ Ws2,
                       u16* __restrict__ W) {
  int i = blockIdx.x * 256 + threadIdx.x;
  if (i >= 1152 * 256) return;
  int oc = i >> 8, k = i & 255;
  int c = oc >> 7, o = oc & 127;
  float v = (c < CC) ? Wc2[c * (DD * HH) + o * HH + k] : Ws2[o * HH + k];
  W[i] = f2bf(v);
}

// ---------------- CSR build over seg = c*N + dst ----------------

__global__ void k_hist(const int* __restrict__ ei, const int* __restrict__ ec,
                       int* __restrict__ counts) {
  int e = blockIdx.x * 256 + threadIdx.x;
  if (e < EE) {
    int dst = ei[EE + e];
    int c = ec[e];
    atomicAdd(&counts[c * NN + dst], 1);
  }
}

__global__ void k_offsets(const int* __restrict__ counts, int2* __restrict__ oc,
                          int* __restrict__ cursor, int* __restrict__ gcount) {
  __shared__ int lds[256];
  __shared__ int basesh;
  int tid = threadIdx.x;
  int i = blockIdx.x * 256 + tid;
  int c = (i < CC * NN) ? counts[i] : 0;
  lds[tid] = c;
  __syncthreads();
  int v = c;
  for (int s = 1; s < 256; s <<= 1) {
    int t = (tid >= s) ? lds[tid - s] : 0;
    __syncthreads();
    v += t;
    lds[tid] = v;
    __syncthreads();
  }
  if (tid == 255) basesh = atomicAdd(gcount, v);
  __syncthreads();
  int excl = basesh + v - c;
  if (i < CC * NN) {
    oc[i] = make_int2(excl, c);
    cursor[i] = excl;
  }
}

__global__ void k_fill(const int* __restrict__ ei, const int* __restrict__ ec,
                       int* __restrict__ cursor, int* __restrict__ ssrc) {
  int e = blockIdx.x * 256 + threadIdx.x;
  if (e < EE) {
    int src = ei[e];
    int dst = ei[EE + e];
    int seg = ec[e] * NN + dst;
    int slot = atomicAdd(&cursor[seg], 1);
    ssrc[slot] = src;
  }
}

// ---------------- layer 1: pure gather (thread = (seg, 32B-chunk)) ----------------
// agg1[seg][128] bf16 = sum of xb[src] rows. 3.2M threads, no LDS/barriers.

__global__ void __launch_bounds__(256) k_agg1(
    const u16* __restrict__ xb, const int2* __restrict__ oc,
    const int* __restrict__ ssrc, u16* __restrict__ agg) {
  int item = blockIdx.x * 256 + threadIdx.x;   // 12500*256 = 3.2M exact
  int seg = item >> 3, ch = item & 7;
  int eoff = ch * 16;
  int2 se = oc[seg];
  float s[16];
#pragma unroll
  for (int q = 0; q < 16; q++) s[q] = 0.f;
  for (int j = 0; j < se.y; j += 4) {
    int idx[4];
#pragma unroll
    for (int t = 0; t < 4; t++) idx[t] = (j + t < se.y) ? ssrc[se.x + j + t] : -1;
#pragma unroll
    for (int t = 0; t < 4; t++) {
      if (idx[t] >= 0) {
        const u16* pp = xb + (size_t)idx[t] * DD + eoff;
        s16x8 lo = *(const s16x8*)pp;
        s16x8 hi = *(const s16x8*)(pp + 8);
#pragma unroll
        for (int q = 0; q < 8; q++) s[q] += bf2f(lo[q]);
#pragma unroll
        for (int q = 0; q < 8; q++) s[q + 8] += bf2f(hi[q]);
      }
    }
  }
  s16x8 lo, hi;
#pragma unroll
  for (int q = 0; q < 8; q++) lo[q] = (short)f2bf(s[q]);
#pragma unroll
  for (int q = 0; q < 8; q++) hi[q] = (short)f2bf(s[q + 8]);
  u16* op = agg + (size_t)seg * DD + eoff;
  *(s16x8*)op = lo;
  *(s16x8*)(op + 8) = hi;
}

// ---------------- layer 1 dense: h = ReLU(agg1 blockdiag Wc1 + x Ws1 + b1) --------
// A streaming from agg1/xb. Wave: 16 rows x 128 cols. Block: 32 rows, 4 waves.

__global__ void __launch_bounds__(256) k_gemm1s(
    const u16* __restrict__ xb, const u16* __restrict__ agg,
    const u16* __restrict__ Wt, const float* __restrict__ b1,
    u16* __restrict__ hb) {
  int tid = threadIdx.x;
  int w = tid >> 6, lane = tid & 63;
  int rs = lane & 15, kg = lane >> 4;
  int rt = w >> 1, ch = w & 1;
  int r0 = blockIdx.x * 32;
  int row = r0 + rt * 16 + rs;
  int rowA = min(row, NN - 1);

  f32x4 acc[8];
#pragma unroll
  for (int i = 0; i < 8; i++)
#pragma unroll
    for (int q = 0; q < 4; q++) acc[i][q] = 0.f;

  for (int c = 0; c < CC; ++c) {
    const u16* ab = agg + ((size_t)c * NN + rowA) * DD;
#pragma unroll
    for (int kk = 0; kk < 4; ++kk) {
      s16x8 af = *(const s16x8*)(ab + kk * 32 + kg * 8);
      int k0 = c * 128 + kk * 32;
#pragma unroll
      for (int fc = 0; fc < 8; ++fc) {
        int col = ch * 128 + fc * 16 + rs;
        s16x8 bfr = *(const s16x8*)(Wt + col * K1 + k0 + kg * 8);
        acc[fc] = __builtin_amdgcn_mfma_f32_16x16x32_bf16(af, bfr, acc[fc], 0, 0, 0);
      }
    }
  }
#pragma unroll
  for (int kk = 0; kk < 4; ++kk) {           // self block
    s16x8 af = *(const s16x8*)(xb + (size_t)rowA * DD + kk * 32 + kg * 8);
    int k0 = CC * DD + kk * 32;
#pragma unroll
    for (int fc = 0; fc < 8; ++fc) {
      int col = ch * 128 + fc * 16 + rs;
      s16x8 bfr = *(const s16x8*)(Wt + col * K1 + k0 + kg * 8);
      acc[fc] = __builtin_amdgcn_mfma_f32_16x16x32_bf16(af, bfr, acc[fc], 0, 0, 0);
    }
  }
#pragma unroll
  for (int fc = 0; fc < 8; ++fc) {
    int col = ch * 128 + fc * 16 + rs;
    float bias = b1[col];
#pragma unroll
    for (int q = 0; q < 4; ++q) {
      float v = acc[fc][q] + bias;
      if (v < 0.f) v = 0.f;
      int rr = r0 + rt * 16 + kg * 4 + q;
      if (rr < NN) hb[rr * HH + col] = f2bf(v);
    }
  }
}

// ---------------- layer 2 multiply-first: g2[n][1152] = h[n] @ Wt2g^T ----------
// Block: 32 rows, 8 waves (512 thr). Wave: 16 rows x 288 cols (18 frags).

__global__ void __launch_bounds__(512) k_gemm2g(
    const u16* __restrict__ hb, const u16* __restrict__ W,
    u16* __restrict__ g2) {
  int tid = threadIdx.x;
  int w = tid >> 6, lane = tid & 63;
  int rs = lane & 15, kg = lane >> 4;
  int rt = w >> 2, ch = w & 3;
  int r0 = blockIdx.x * 32;
  int row = r0 + rt * 16 + rs;
  int rowA = min(row, NN - 1);

  f32x4 acc[18];
#pragma unroll
  for (int i = 0; i < 18; i++)
#pragma unroll
    for (int q = 0; q < 4; q++) acc[i][q] = 0.f;

#pragma unroll
  for (int kk = 0; kk < 8; ++kk) {
    s16x8 af = *(const s16x8*)(hb + (size_t)rowA * HH + kk * 32 + kg * 8);
#pragma unroll
    for (int fc = 0; fc < 18; ++fc) {
      int col = ch * 288 + fc * 16 + rs;
      s16x8 bfr = *(const s16x8*)(W + col * 256 + kk * 32 + kg * 8);
      acc[fc] = __builtin_amdgcn_mfma_f32_16x16x32_bf16(af, bfr, acc[fc], 0, 0, 0);
    }
  }
#pragma unroll
  for (int fc = 0; fc < 18; ++fc) {
    int col = ch * 288 + fc * 16 + rs;
#pragma unroll
    for (int q = 0; q < 4; ++q) {
      int rr = r0 + rt * 16 + kg * 4 + q;
      if (rr < NN) g2[(size_t)rr * 1152 + col] = f2bf(acc[fc][q]);
    }
  }
}

// ---------------- layer 2 final: gather-sum-sigmoid (no MFMA) ----------------
// out[dst][128] = sigmoid(b2 + g2self[dst] + sum_{c,e} g2[src][c*128..] - 10).
// Thread = (dst, 32B-chunk); 400k threads.

__global__ void __launch_bounds__(256) k_final(
    const u16* __restrict__ g2, const float* __restrict__ b2,
    const int2* __restrict__ oc, const int* __restrict__ ssrc,
    float* __restrict__ out) {
  int item = blockIdx.x * 256 + threadIdx.x;
  if (item >= NN * 8) return;
  int dst = item >> 3, ch = item & 7;
  int eoff = ch * 16;

  int2 se[CC];
#pragma unroll
  for (int c = 0; c < CC; ++c) se[c] = oc[c * NN + dst];

  float s[16];
  {
    const u16* sp = g2 + (size_t)dst * 1152 + 1024 + eoff;
    s16x8 lo = *(const s16x8*)sp;
    s16x8 hi = *(const s16x8*)(sp + 8);
#pragma unroll
    for (int q = 0; q < 8; q++) s[q] = b2[eoff + q] + bf2f(lo[q]);
#pragma unroll
    for (int q = 0; q < 8; q++) s[q + 8] = b2[eoff + 8 + q] + bf2f(hi[q]);
  }
#pragma unroll
  for (int c = 0; c < CC; ++c) {
    int st = se[c].x, cn = se[c].y;
    int cbase = c * 128 + eoff;
    for (int j = 0; j < cn; j += 4) {
      int idx[4];
#pragma unroll
      for (int t = 0; t < 4; t++) idx[t] = (j + t < cn) ? ssrc[st + j + t] : -1;
#pragma unroll
      for (int t = 0; t < 4; t++) {
        if (idx[t] >= 0) {
          const u16* pp = g2 + (size_t)idx[t] * 1152 + cbase;
          s16x8 lo = *(const s16x8*)pp;
          s16x8 hi = *(const s16x8*)(pp + 8);
#pragma unroll
          for (int q = 0; q < 8; q++) s[q] += bf2f(lo[q]);
#pragma unroll
          for (int q = 0; q < 8; q++) s[q + 8] += bf2f(hi[q]);
        }
      }
    }
  }
  float* op = out + (size_t)dst * DD + eoff;
#pragma unroll
  for (int q = 0; q < 16; q++) op[q] = 1.f / (1.f + expf(10.f - s[q]));
}

// ---------------- launch ----------------

extern "C" void kernel_launch(void* const* d_in, const int* in_sizes, int n_in,
                              void* d_out, int out_size, void* d_ws, size_t ws_size,
                              hipStream_t stream) {
  const float* x   = (const float*)d_in[0];
  const int*   ei  = (const int*)d_in[1];
  const int*   ec  = (const int*)d_in[2];
  const float* Ws1 = (const float*)d_in[3];
  const float* b1  = (const float*)d_in[4];
  const float* Ws2 = (const float*)d_in[5];
  const float* b2  = (const float*)d_in[6];
  const float* Wc1 = (const float*)d_in[7];
  const float* Wc2 = (const float*)d_in[8];
  float* out = (float*)d_out;

  char* p = (char*)d_ws;
  // g2 [N,1152] bf16 (115.2MB) aliases agg1 (102.4MB) + xb (12.8MB):
  // agg1/xb are dead before k_gemm2g writes g2.
  u16*  g2     = (u16*)p;
  u16*  agg1   = (u16*)p;                         // [C*N,128] bf16
  u16*  xb     = (u16*)(p + 102400000);           // [N,128] bf16
  u16*  hb     = (u16*)(p + 115200000);           // [N,256] bf16
  u16*  Wt1    = (u16*)(p + 140800000);           // [256,1152] bf16
  u16*  Wt2g   = (u16*)(p + 141389824);           // [1152,256] bf16
  int2* oc     = (int2*)(p + 141979648);          // [C*N] {off,cnt}
  int*  ssrc   = (int*)(p + 145179648);           // [E]
  int*  counts = (int*)(p + 148379648);           // [C*N]
  int*  gcount = (int*)(p + 149979648);           // scan base
  int*  cursor = (int*)(p + 149979904);           // [C*N]

  hipMemsetAsync(counts, 0, 1600256, stream);     // counts + gcount

  k_castx<<<25000, 256, 0, stream>>>(x, xb);
  k_wt1<<<1152, 256, 0, stream>>>(Wc1, Ws1, Wt1);
  k_wt2g<<<1152, 256, 0, stream>>>(Wc2, Ws2, Wt2g);

  k_hist<<<3125, 256, 0, stream>>>(ei, ec, counts);
  k_offsets<<<1563, 256, 0, stream>>>(counts, oc, cursor, gcount);
  k_fill<<<3125, 256, 0, stream>>>(ei, ec, cursor, ssrc);

  k_agg1<<<12500, 256, 0, stream>>>(xb, oc, ssrc, agg1);
  k_gemm1s<<<1563, 256, 0, stream>>>(xb, agg1, Wt1, b1, hb);
  k_gemm2g<<<1563, 512, 0, stream>>>(hb, Wt2g, g2);
  k_final<<<1563, 256, 0, stream>>>(g2, b2, oc, ssrc, out);
}

// Round 13
// 464.652 us; speedup vs baseline: 1.7004x; 1.5605x over previous
//
#include <hip/hip_runtime.h>

// GNN: 2-layer edge-coloured conv on MI355X.
// Round 13: (1) fragment-major weight layouts -> coalesced 1KB B-loads;
// (2) k_gemm2g re-tiled 64x384, acc[12], higher occupancy; (3) CSR keyed by
// dst*8+c -> static colour loops, balanced gathers (max-of-4 Poisson16).

#define NN 50000
#define EE 800000
#define DD 128
#define HH 256
#define CC 8
#define K1 1152   // C*D + D

typedef unsigned short u16;
typedef __attribute__((ext_vector_type(8))) short s16x8;
typedef __attribute__((ext_vector_type(4))) float f32x4;

__device__ __forceinline__ float bf2f(short u) {
  return __uint_as_float(((unsigned)(u16)u) << 16);
}
__device__ __forceinline__ u16 f2bf(float f) {
  unsigned u = __float_as_uint(f);
  u = (u + 0x7FFFu + ((u >> 16) & 1u)) >> 16;   // RNE
  return (u16)u;
}

// ---------------- prep ----------------

__global__ void k_castx(const float* __restrict__ x, u16* __restrict__ xb) {
  int i = blockIdx.x * 256 + threadIdx.x;
  if (i < NN * DD) xb[i] = f2bf(x[i]);
}

// W1f fragment-major: idx = (((col16*36 + kk)*4 + kg)*16 + rs)*8 + e
// col = col16*16+rs (0..255), k = kk*32+kg*8+e (0..1151)
__global__ void k_wt1f(const float* __restrict__ Wc1, const float* __restrict__ Ws1,
                       u16* __restrict__ W) {
  int i = blockIdx.x * 256 + threadIdx.x;   // 294912 total, grid 1152
  if (i >= 294912) return;
  int e = i & 7;
  int t = i >> 3;
  int rs = t & 15; t >>= 4;
  int kg = t & 3;  t >>= 2;
  int kk = t % 36;
  int col16 = t / 36;
  int col = col16 * 16 + rs;
  int k = kk * 32 + kg * 8 + e;
  float v = (k < CC * DD) ? Wc1[(k >> 7) * (HH * DD) + col * DD + (k & 127)]
                          : Ws1[col * DD + (k - CC * DD)];
  W[i] = f2bf(v);
}

// W2f fragment-major: idx = (((col16*8 + kk)*4 + kg)*16 + rs)*8 + e
// oc = col16*16+rs (0..1151): c=oc>>7, o=oc&127; k = kk*32+kg*8+e (0..255)
__global__ void k_wt2f(const float* __restrict__ Wc2, const float* __restrict__ Ws2,
                       u16* __restrict__ W) {
  int i = blockIdx.x * 256 + threadIdx.x;   // 294912 total, grid 1152
  if (i >= 294912) return;
  int e = i & 7;
  int t = i >> 3;
  int rs = t & 15; t >>= 4;
  int kg = t & 3;  t >>= 2;
  int kk = t & 7;
  int col16 = t >> 3;
  int oc = col16 * 16 + rs;
  int c = oc >> 7, o = oc & 127;
  int k = kk * 32 + kg * 8 + e;
  float v = (c < CC) ? Wc2[c * (DD * HH) + o * HH + k] : Ws2[o * HH + k];
  W[i] = f2bf(v);
}

// ---------------- CSR build over seg = dst*8 + c (colour segs contiguous) ------

__global__ void k_hist(const int* __restrict__ ei, const int* __restrict__ ec,
                       int* __restrict__ counts) {
  int e = blockIdx.x * 256 + threadIdx.x;
  if (e < EE) {
    int dst = ei[EE + e];
    int c = ec[e];
    atomicAdd(&counts[dst * CC + c], 1);
  }
}

__global__ void k_offsets(const int* __restrict__ counts, int2* __restrict__ oc,
                          int* __restrict__ cursor, int* __restrict__ gcount) {
  __shared__ int lds[256];
  __shared__ int basesh;
  int tid = threadIdx.x;
  int i = blockIdx.x * 256 + tid;
  int c = (i < CC * NN) ? counts[i] : 0;
  lds[tid] = c;
  __syncthreads();
  int v = c;
  for (int s = 1; s < 256; s <<= 1) {
    int t = (tid >= s) ? lds[tid - s] : 0;
    __syncthreads();
    v += t;
    lds[tid] = v;
    __syncthreads();
  }
  if (tid == 255) basesh = atomicAdd(gcount, v);
  __syncthreads();
  int excl = basesh + v - c;
  if (i < CC * NN) {
    oc[i] = make_int2(excl, c);
    cursor[i] = excl;
  }
}

__global__ void k_fill(const int* __restrict__ ei, const int* __restrict__ ec,
                       int* __restrict__ cursor, int* __restrict__ ssrc) {
  int e = blockIdx.x * 256 + threadIdx.x;
  if (e < EE) {
    int src = ei[e];
    int dst = ei[EE + e];
    int slot = atomicAdd(&cursor[dst * CC + ec[e]], 1);
    ssrc[slot] = src;
  }
}

// ---------------- layer 1: balanced pure gather ----------------
// thread = (dst, 16B-chunk of 128 feats): 50000*16 = 800k threads, grid 3125.
// Static colour loop; per-colour acc flushed -> 8 live fp32 regs.

__global__ void __launch_bounds__(256) k_agg1(
    const u16* __restrict__ xb, const int2* __restrict__ oc,
    const int* __restrict__ ssrc, u16* __restrict__ agg) {
  int item = blockIdx.x * 256 + threadIdx.x;   // exact
  int dst = item >> 4, ch = item & 15;
  int eoff = ch * 8;
#pragma unroll
  for (int c = 0; c < CC; ++c) {
    int2 se = oc[dst * CC + c];
    float s[8];
#pragma unroll
    for (int q = 0; q < 8; q++) s[q] = 0.f;
    int j = 0;
    for (; j + 1 < se.y; j += 2) {
      int s0 = ssrc[se.x + j];
      int s1 = ssrc[se.x + j + 1];
      s16x8 v0 = *(const s16x8*)(xb + (size_t)s0 * DD + eoff);
      s16x8 v1 = *(const s16x8*)(xb + (size_t)s1 * DD + eoff);
#pragma unroll
      for (int q = 0; q < 8; q++) s[q] += bf2f(v0[q]) + bf2f(v1[q]);
    }
    if (j < se.y) {
      int s0 = ssrc[se.x + j];
      s16x8 v0 = *(const s16x8*)(xb + (size_t)s0 * DD + eoff);
#pragma unroll
      for (int q = 0; q < 8; q++) s[q] += bf2f(v0[q]);
    }
    s16x8 r;
#pragma unroll
    for (int q = 0; q < 8; q++) r[q] = (short)f2bf(s[q]);
    *(s16x8*)(agg + ((size_t)c * NN + dst) * DD + eoff) = r;
  }
}

// ---------------- layer 1 dense: h = ReLU(agg blockdiag Wc1 + x Ws1 + b1) ------
// Wave: 16 rows x 128 cols, acc[8]. Block 32 rows, 4 waves (2rt x 2ch).
// B from W1f: one coalesced 1KB load per (fc,kk).

__global__ void __launch_bounds__(256) k_gemm1s(
    const u16* __restrict__ xb, const u16* __restrict__ agg,
    const u16* __restrict__ Wf, const float* __restrict__ b1,
    u16* __restrict__ hb) {
  int tid = threadIdx.x;
  int w = tid >> 6, lane = tid & 63;
  int rs = lane & 15, kg = lane >> 4;
  int rt = w >> 1, ch = w & 1;
  int r0 = blockIdx.x * 32;
  int row = r0 + rt * 16 + rs;
  int rowA = min(row, NN - 1);

  f32x4 acc[8];
#pragma unroll
  for (int i = 0; i < 8; i++)
#pragma unroll
    for (int q = 0; q < 4; q++) acc[i][q] = 0.f;

  for (int c = 0; c < CC; ++c) {
    const u16* ab = agg + ((size_t)c * NN + rowA) * DD;
#pragma unroll
    for (int kk = 0; kk < 4; ++kk) {
      s16x8 af = *(const s16x8*)(ab + kk * 32 + kg * 8);
      int kkg = c * 4 + kk;
#pragma unroll
      for (int fc = 0; fc < 8; ++fc) {
        int col16 = ch * 8 + fc;
        s16x8 bfr = *(const s16x8*)(Wf + (size_t)(col16 * 36 + kkg) * 512 + lane * 8);
        acc[fc] = __builtin_amdgcn_mfma_f32_16x16x32_bf16(af, bfr, acc[fc], 0, 0, 0);
      }
    }
  }
#pragma unroll
  for (int kk = 0; kk < 4; ++kk) {           // self block (k 1024..1151)
    s16x8 af = *(const s16x8*)(xb + (size_t)rowA * DD + kk * 32 + kg * 8);
    int kkg = 32 + kk;
#pragma unroll
    for (int fc = 0; fc < 8; ++fc) {
      int col16 = ch * 8 + fc;
      s16x8 bfr = *(const s16x8*)(Wf + (size_t)(col16 * 36 + kkg) * 512 + lane * 8);
      acc[fc] = __builtin_amdgcn_mfma_f32_16x16x32_bf16(af, bfr, acc[fc], 0, 0, 0);
    }
  }
#pragma unroll
  for (int fc = 0; fc < 8; ++fc) {
    int col = ch * 128 + fc * 16 + rs;
    float bias = b1[col];
#pragma unroll
    for (int q = 0; q < 4; ++q) {
      float v = acc[fc][q] + bias;
      if (v < 0.f) v = 0.f;
      int rr = r0 + rt * 16 + kg * 4 + q;
      if (rr < NN) hb[(size_t)rr * HH + col] = f2bf(v);
    }
  }
}

// ---------------- layer 2 multiply-first: g2[n][1152] = h[n] @ W2^T ------------
// Grid (3 colblocks, 782 rowblocks). Block 512 thr = 8 waves (4rt x 2ch);
// tile 64 rows x 384 cols; wave 16 x 192, acc[12]. Coalesced B from W2f.

__global__ void __launch_bounds__(512) k_gemm2g(
    const u16* __restrict__ hb, const u16* __restrict__ Wf,
    u16* __restrict__ g2) {
  int cb = blockIdx.x;          // 0..2
  int rb = blockIdx.y;          // 0..781
  int tid = threadIdx.x;
  int w = tid >> 6, lane = tid & 63;
  int rs = lane & 15, kg = lane >> 4;
  int rt = w >> 1, ch = w & 1;
  int r0 = rb * 64;
  int row = r0 + rt * 16 + rs;
  int rowA = min(row, NN - 1);
  int c16b = cb * 24 + ch * 12;

  f32x4 acc[12];
#pragma unroll
  for (int i = 0; i < 12; i++)
#pragma unroll
    for (int q = 0; q < 4; q++) acc[i][q] = 0.f;

#pragma unroll
  for (int kk = 0; kk < 8; ++kk) {
    s16x8 af = *(const s16x8*)(hb + (size_t)rowA * HH + kk * 32 + kg * 8);
#pragma unroll
    for (int fc = 0; fc < 12; ++fc) {
      s16x8 bfr = *(const s16x8*)(Wf + (size_t)((c16b + fc) * 8 + kk) * 512 + lane * 8);
      acc[fc] = __builtin_amdgcn_mfma_f32_16x16x32_bf16(af, bfr, acc[fc], 0, 0, 0);
    }
  }
#pragma unroll
  for (int q = 0; q < 4; ++q) {
    int rr = r0 + rt * 16 + kg * 4 + q;
    if (rr < NN) {
#pragma unroll
      for (int fc = 0; fc < 12; ++fc) {
        int col = (c16b + fc) * 16 + rs;
        g2[(size_t)rr * 1152 + col] = f2bf(acc[fc][q]);
      }
    }
  }
}

// ---------------- layer 2 final: balanced gather-sum-sigmoid -------------------
// thread = (dst, 32B-chunk): 400k threads. Static colour loop over contiguous
// segments; per edge 8 threads read 256B contiguous of g2[src].

__global__ void __launch_bounds__(256) k_final(
    const u16* __restrict__ g2, const float* __restrict__ b2,
    const int2* __restrict__ oc, const int* __restrict__ ssrc,
    float* __restrict__ out) {
  int item = blockIdx.x * 256 + threadIdx.x;
  if (item >= NN * 8) return;
  int dst = item >> 3, ch = item & 7;
  int eoff = ch * 16;

  float s[16];
  {
    const u16* sp = g2 + (size_t)dst * 1152 + 1024 + eoff;
    s16x8 lo = *(const s16x8*)sp;
    s16x8 hi = *(const s16x8*)(sp + 8);
#pragma unroll
    for (int q = 0; q < 8; q++) s[q] = b2[eoff + q] + bf2f(lo[q]);
#pragma unroll
    for (int q = 0; q < 8; q++) s[q + 8] = b2[eoff + 8 + q] + bf2f(hi[q]);
  }
#pragma unroll
  for (int c = 0; c < CC; ++c) {
    int2 se = oc[dst * CC + c];
    int cbase = c * 128 + eoff;
    int j = 0;
    for (; j + 1 < se.y; j += 2) {
      int s0 = ssrc[se.x + j];
      int s1 = ssrc[se.x + j + 1];
      const u16* p0 = g2 + (size_t)s0 * 1152 + cbase;
      const u16* p1 = g2 + (size_t)s1 * 1152 + cbase;
      s16x8 a0 = *(const s16x8*)p0, b0 = *(const s16x8*)(p0 + 8);
      s16x8 a1 = *(const s16x8*)p1, b1v = *(const s16x8*)(p1 + 8);
#pragma unroll
      for (int q = 0; q < 8; q++) s[q] += bf2f(a0[q]) + bf2f(a1[q]);
#pragma unroll
      for (int q = 0; q < 8; q++) s[q + 8] += bf2f(b0[q]) + bf2f(b1v[q]);
    }
    if (j < se.y) {
      int s0 = ssrc[se.x + j];
      const u16* p0 = g2 + (size_t)s0 * 1152 + cbase;
      s16x8 a0 = *(const s16x8*)p0, b0 = *(const s16x8*)(p0 + 8);
#pragma unroll
      for (int q = 0; q < 8; q++) s[q] += bf2f(a0[q]);
#pragma unroll
      for (int q = 0; q < 8; q++) s[q + 8] += bf2f(b0[q]);
    }
  }
  float* op = out + (size_t)dst * DD + eoff;
#pragma unroll
  for (int q = 0; q < 16; q++) op[q] = 1.f / (1.f + expf(10.f - s[q]));
}

// ---------------- launch ----------------

extern "C" void kernel_launch(void* const* d_in, const int* in_sizes, int n_in,
                              void* d_out, int out_size, void* d_ws, size_t ws_size,
                              hipStream_t stream) {
  const float* x   = (const float*)d_in[0];
  const int*   ei  = (const int*)d_in[1];
  const int*   ec  = (const int*)d_in[2];
  const float* Ws1 = (const float*)d_in[3];
  const float* b1  = (const float*)d_in[4];
  const float* Ws2 = (const float*)d_in[5];
  const float* b2  = (const float*)d_in[6];
  const float* Wc1 = (const float*)d_in[7];
  const float* Wc2 = (const float*)d_in[8];
  float* out = (float*)d_out;

  char* p = (char*)d_ws;
  // g2 [N,1152] bf16 (115.2MB) aliases agg1 (102.4MB) + xb (12.8MB):
  // agg1/xb are dead before k_gemm2g writes g2.
  u16*  g2     = (u16*)p;
  u16*  agg1   = (u16*)p;                         // [C*N,128] bf16
  u16*  xb     = (u16*)(p + 102400000);           // [N,128] bf16
  u16*  hb     = (u16*)(p + 115200000);           // [N,256] bf16
  u16*  W1f    = (u16*)(p + 140800000);           // frag-major [16][36][4][16][8]
  u16*  W2f    = (u16*)(p + 141389824);           // frag-major [72][8][4][16][8]
  int2* oc     = (int2*)(p + 141979648);          // [N*C] {off,cnt}, seg=dst*8+c
  int*  ssrc   = (int*)(p + 145179648);           // [E]
  int*  counts = (int*)(p + 148379648);           // [N*C]
  int*  gcount = (int*)(p + 149979648);           // scan base
  int*  cursor = (int*)(p + 149979904);           // [N*C]

  hipMemsetAsync(counts, 0, 1600256, stream);     // counts + gcount

  k_castx<<<25000, 256, 0, stream>>>(x, xb);
  k_wt1f<<<1152, 256, 0, stream>>>(Wc1, Ws1, W1f);
  k_wt2f<<<1152, 256, 0, stream>>>(Wc2, Ws2, W2f);

  k_hist<<<3125, 256, 0, stream>>>(ei, ec, counts);
  k_offsets<<<1563, 256, 0, stream>>>(counts, oc, cursor, gcount);
  k_fill<<<3125, 256, 0, stream>>>(ei, ec, cursor, ssrc);

  k_agg1<<<3125, 256, 0, stream>>>(xb, oc, ssrc, agg1);
  k_gemm1s<<<1563, 256, 0, stream>>>(xb, agg1, W1f, b1, hb);
  k_gemm2g<<<dim3(3, 782), 512, 0, stream>>>(hb, W2f, g2);
  k_final<<<1563, 256, 0, stream>>>(g2, b2, oc, ssrc, out);
}

// Round 14
// 364.406 us; speedup vs baseline: 2.1681x; 1.2751x over previous
//
#include <hip/hip_runtime.h>

// GNN: 2-layer edge-coloured conv on MI355X.
// Round 14: 64-row waves for both GEMMs (4 row-groups in registers) ->
// B-panel traffic /4 (1.8GB -> 460MB) and 32:12 MFMA:load inner step.

#define NN 50000
#define EE 800000
#define DD 128
#define HH 256
#define CC 8
#define K1 1152   // C*D + D

typedef unsigned short u16;
typedef __attribute__((ext_vector_type(8))) short s16x8;
typedef __attribute__((ext_vector_type(4))) float f32x4;

__device__ __forceinline__ float bf2f(short u) {
  return __uint_as_float(((unsigned)(u16)u) << 16);
}
__device__ __forceinline__ u16 f2bf(float f) {
  unsigned u = __float_as_uint(f);
  u = (u + 0x7FFFu + ((u >> 16) & 1u)) >> 16;   // RNE
  return (u16)u;
}

// ---------------- prep ----------------

__global__ void k_castx(const float* __restrict__ x, u16* __restrict__ xb) {
  int i = blockIdx.x * 256 + threadIdx.x;
  if (i < NN * DD) xb[i] = f2bf(x[i]);
}

// W1f fragment-major: idx = (((col16*36 + kk)*4 + kg)*16 + rs)*8 + e
__global__ void k_wt1f(const float* __restrict__ Wc1, const float* __restrict__ Ws1,
                       u16* __restrict__ W) {
  int i = blockIdx.x * 256 + threadIdx.x;
  if (i >= 294912) return;
  int e = i & 7;
  int t = i >> 3;
  int rs = t & 15; t >>= 4;
  int kg = t & 3;  t >>= 2;
  int kk = t % 36;
  int col16 = t / 36;
  int col = col16 * 16 + rs;
  int k = kk * 32 + kg * 8 + e;
  float v = (k < CC * DD) ? Wc1[(k >> 7) * (HH * DD) + col * DD + (k & 127)]
                          : Ws1[col * DD + (k - CC * DD)];
  W[i] = f2bf(v);
}

// W2f fragment-major: idx = (((col16*8 + kk)*4 + kg)*16 + rs)*8 + e
__global__ void k_wt2f(const float* __restrict__ Wc2, const float* __restrict__ Ws2,
                       u16* __restrict__ W) {
  int i = blockIdx.x * 256 + threadIdx.x;
  if (i >= 294912) return;
  int e = i & 7;
  int t = i >> 3;
  int rs = t & 15; t >>= 4;
  int kg = t & 3;  t >>= 2;
  int kk = t & 7;
  int col16 = t >> 3;
  int oc = col16 * 16 + rs;
  int c = oc >> 7, o = oc & 127;
  int k = kk * 32 + kg * 8 + e;
  float v = (c < CC) ? Wc2[c * (DD * HH) + o * HH + k] : Ws2[o * HH + k];
  W[i] = f2bf(v);
}

// ---------------- CSR build over seg = dst*8 + c ----------------

__global__ void k_hist(const int* __restrict__ ei, const int* __restrict__ ec,
                       int* __restrict__ counts) {
  int e = blockIdx.x * 256 + threadIdx.x;
  if (e < EE) {
    int dst = ei[EE + e];
    int c = ec[e];
    atomicAdd(&counts[dst * CC + c], 1);
  }
}

__global__ void k_offsets(const int* __restrict__ counts, int2* __restrict__ oc,
                          int* __restrict__ cursor, int* __restrict__ gcount) {
  __shared__ int lds[256];
  __shared__ int basesh;
  int tid = threadIdx.x;
  int i = blockIdx.x * 256 + tid;
  int c = (i < CC * NN) ? counts[i] : 0;
  lds[tid] = c;
  __syncthreads();
  int v = c;
  for (int s = 1; s < 256; s <<= 1) {
    int t = (tid >= s) ? lds[tid - s] : 0;
    __syncthreads();
    v += t;
    lds[tid] = v;
    __syncthreads();
  }
  if (tid == 255) basesh = atomicAdd(gcount, v);
  __syncthreads();
  int excl = basesh + v - c;
  if (i < CC * NN) {
    oc[i] = make_int2(excl, c);
    cursor[i] = excl;
  }
}

__global__ void k_fill(const int* __restrict__ ei, const int* __restrict__ ec,
                       int* __restrict__ cursor, int* __restrict__ ssrc) {
  int e = blockIdx.x * 256 + threadIdx.x;
  if (e < EE) {
    int src = ei[e];
    int dst = ei[EE + e];
    int slot = atomicAdd(&cursor[dst * CC + ec[e]], 1);
    ssrc[slot] = src;
  }
}

// ---------------- layer 1: balanced pure gather ----------------
// thread = (dst, 16B-chunk): 800k threads, grid 3125.

__global__ void __launch_bounds__(256) k_agg1(
    const u16* __restrict__ xb, const int2* __restrict__ oc,
    const int* __restrict__ ssrc, u16* __restrict__ agg) {
  int item = blockIdx.x * 256 + threadIdx.x;
  int dst = item >> 4, ch = item & 15;
  int eoff = ch * 8;
#pragma unroll
  for (int c = 0; c < CC; ++c) {
    int2 se = oc[dst * CC + c];
    float s[8];
#pragma unroll
    for (int q = 0; q < 8; q++) s[q] = 0.f;
    int j = 0;
    for (; j + 1 < se.y; j += 2) {
      int s0 = ssrc[se.x + j];
      int s1 = ssrc[se.x + j + 1];
      s16x8 v0 = *(const s16x8*)(xb + (size_t)s0 * DD + eoff);
      s16x8 v1 = *(const s16x8*)(xb + (size_t)s1 * DD + eoff);
#pragma unroll
      for (int q = 0; q < 8; q++) s[q] += bf2f(v0[q]) + bf2f(v1[q]);
    }
    if (j < se.y) {
      int s0 = ssrc[se.x + j];
      s16x8 v0 = *(const s16x8*)(xb + (size_t)s0 * DD + eoff);
#pragma unroll
      for (int q = 0; q < 8; q++) s[q] += bf2f(v0[q]);
    }
    s16x8 r;
#pragma unroll
    for (int q = 0; q < 8; q++) r[q] = (short)f2bf(s[q]);
    *(s16x8*)(agg + ((size_t)c * NN + dst) * DD + eoff) = r;
  }
}

// ---------------- layer 1 dense: 64-row waves ----------------
// Wave: 64 rows x 128 cols, acc[4][8]. Block 4 waves (2rt x 2ch) = 128 x 256.
// Grid 391. Inner step: 4 af + 8 bfr -> 32 MFMA.

__global__ void __launch_bounds__(256, 2) k_gemm1s(
    const u16* __restrict__ xb, const u16* __restrict__ agg,
    const u16* __restrict__ Wf, const float* __restrict__ b1,
    u16* __restrict__ hb) {
  int tid = threadIdx.x;
  int w = tid >> 6, lane = tid & 63;
  int rs = lane & 15, kg = lane >> 4;
  int rt = w >> 1, ch = w & 1;
  int r0 = blockIdx.x * 128 + rt * 64;

  int rowA[4];
#pragma unroll
  for (int rg = 0; rg < 4; ++rg) rowA[rg] = min(r0 + rg * 16 + rs, NN - 1);

  f32x4 acc[4][8];
#pragma unroll
  for (int rg = 0; rg < 4; ++rg)
#pragma unroll
    for (int i = 0; i < 8; i++)
#pragma unroll
      for (int q = 0; q < 4; q++) acc[rg][i][q] = 0.f;

  for (int c = 0; c < CC; ++c) {
#pragma unroll
    for (int kk = 0; kk < 4; ++kk) {
      int kkg = c * 4 + kk;
      s16x8 af[4];
#pragma unroll
      for (int rg = 0; rg < 4; ++rg)
        af[rg] = *(const s16x8*)(agg + ((size_t)c * NN + rowA[rg]) * DD + kk * 32 + kg * 8);
#pragma unroll
      for (int fc = 0; fc < 8; ++fc) {
        int col16 = ch * 8 + fc;
        s16x8 bfr = *(const s16x8*)(Wf + (size_t)(col16 * 36 + kkg) * 512 + lane * 8);
#pragma unroll
        for (int rg = 0; rg < 4; ++rg)
          acc[rg][fc] = __builtin_amdgcn_mfma_f32_16x16x32_bf16(af[rg], bfr, acc[rg][fc], 0, 0, 0);
      }
    }
  }
#pragma unroll
  for (int kk = 0; kk < 4; ++kk) {           // self block (k 1024..1151)
    int kkg = 32 + kk;
    s16x8 af[4];
#pragma unroll
    for (int rg = 0; rg < 4; ++rg)
      af[rg] = *(const s16x8*)(xb + (size_t)rowA[rg] * DD + kk * 32 + kg * 8);
#pragma unroll
    for (int fc = 0; fc < 8; ++fc) {
      int col16 = ch * 8 + fc;
      s16x8 bfr = *(const s16x8*)(Wf + (size_t)(col16 * 36 + kkg) * 512 + lane * 8);
#pragma unroll
      for (int rg = 0; rg < 4; ++rg)
        acc[rg][fc] = __builtin_amdgcn_mfma_f32_16x16x32_bf16(af[rg], bfr, acc[rg][fc], 0, 0, 0);
    }
  }

#pragma unroll
  for (int fc = 0; fc < 8; ++fc) {
    int col = ch * 128 + fc * 16 + rs;
    float bias = b1[col];
#pragma unroll
    for (int rg = 0; rg < 4; ++rg) {
#pragma unroll
      for (int q = 0; q < 4; ++q) {
        float v = acc[rg][fc][q] + bias;
        if (v < 0.f) v = 0.f;
        int rr = r0 + rg * 16 + kg * 4 + q;
        if (rr < NN) hb[(size_t)rr * HH + col] = f2bf(v);
      }
    }
  }
}

// ---------------- layer 2 multiply-first: 64-row waves ----------------
// Wave: 64 rows x 96 cols, acc[4][6]. Block 4 ch-waves = 64 x 384.
// Grid (3 colblocks, 782 rowblocks).

__global__ void __launch_bounds__(256, 3) k_gemm2g(
    const u16* __restrict__ hb, const u16* __restrict__ Wf,
    u16* __restrict__ g2) {
  int cb = blockIdx.x;          // 0..2
  int rb = blockIdx.y;          // 0..781
  int tid = threadIdx.x;
  int ch = tid >> 6, lane = tid & 63;
  int rs = lane & 15, kg = lane >> 4;
  int r0 = rb * 64;
  int c16b = cb * 24 + ch * 6;

  int rowA[4];
#pragma unroll
  for (int rg = 0; rg < 4; ++rg) rowA[rg] = min(r0 + rg * 16 + rs, NN - 1);

  f32x4 acc[4][6];
#pragma unroll
  for (int rg = 0; rg < 4; ++rg)
#pragma unroll
    for (int i = 0; i < 6; i++)
#pragma unroll
      for (int q = 0; q < 4; q++) acc[rg][i][q] = 0.f;

#pragma unroll
  for (int kk = 0; kk < 8; ++kk) {
    s16x8 af[4];
#pragma unroll
    for (int rg = 0; rg < 4; ++rg)
      af[rg] = *(const s16x8*)(hb + (size_t)rowA[rg] * HH + kk * 32 + kg * 8);
#pragma unroll
    for (int fc = 0; fc < 6; ++fc) {
      s16x8 bfr = *(const s16x8*)(Wf + (size_t)((c16b + fc) * 8 + kk) * 512 + lane * 8);
#pragma unroll
      for (int rg = 0; rg < 4; ++rg)
        acc[rg][fc] = __builtin_amdgcn_mfma_f32_16x16x32_bf16(af[rg], bfr, acc[rg][fc], 0, 0, 0);
    }
  }
#pragma unroll
  for (int rg = 0; rg < 4; ++rg) {
#pragma unroll
    for (int q = 0; q < 4; ++q) {
      int rr = r0 + rg * 16 + kg * 4 + q;
      if (rr < NN) {
#pragma unroll
        for (int fc = 0; fc < 6; ++fc) {
          int col = (c16b + fc) * 16 + rs;
          g2[(size_t)rr * 1152 + col] = f2bf(acc[rg][fc][q]);
        }
      }
    }
  }
}

// ---------------- layer 2 final: balanced gather-sum-sigmoid ----------------

__global__ void __launch_bounds__(256) k_final(
    const u16* __restrict__ g2, const float* __restrict__ b2,
    const int2* __restrict__ oc, const int* __restrict__ ssrc,
    float* __restrict__ out) {
  int item = blockIdx.x * 256 + threadIdx.x;
  if (item >= NN * 8) return;
  int dst = item >> 3, ch = item & 7;
  int eoff = ch * 16;

  float s[16];
  {
    const u16* sp = g2 + (size_t)dst * 1152 + 1024 + eoff;
    s16x8 lo = *(const s16x8*)sp;
    s16x8 hi = *(const s16x8*)(sp + 8);
#pragma unroll
    for (int q = 0; q < 8; q++) s[q] = b2[eoff + q] + bf2f(lo[q]);
#pragma unroll
    for (int q = 0; q < 8; q++) s[q + 8] = b2[eoff + 8 + q] + bf2f(hi[q]);
  }
#pragma unroll
  for (int c = 0; c < CC; ++c) {
    int2 se = oc[dst * CC + c];
    int cbase = c * 128 + eoff;
    int j = 0;
    for (; j + 1 < se.y; j += 2) {
      int s0 = ssrc[se.x + j];
      int s1 = ssrc[se.x + j + 1];
      const u16* p0 = g2 + (size_t)s0 * 1152 + cbase;
      const u16* p1 = g2 + (size_t)s1 * 1152 + cbase;
      s16x8 a0 = *(const s16x8*)p0, b0 = *(const s16x8*)(p0 + 8);
      s16x8 a1 = *(const s16x8*)p1, b1v = *(const s16x8*)(p1 + 8);
#pragma unroll
      for (int q = 0; q < 8; q++) s[q] += bf2f(a0[q]) + bf2f(a1[q]);
#pragma unroll
      for (int q = 0; q < 8; q++) s[q + 8] += bf2f(b0[q]) + bf2f(b1v[q]);
    }
    if (j < se.y) {
      int s0 = ssrc[se.x + j];
      const u16* p0 = g2 + (size_t)s0 * 1152 + cbase;
      s16x8 a0 = *(const s16x8*)p0, b0 = *(const s16x8*)(p0 + 8);
#pragma unroll
      for (int q = 0; q < 8; q++) s[q] += bf2f(a0[q]);
#pragma unroll
      for (int q = 0; q < 8; q++) s[q + 8] += bf2f(b0[q]);
    }
  }
  float* op = out + (size_t)dst * DD + eoff;
#pragma unroll
  for (int q = 0; q < 16; q++) op[q] = 1.f / (1.f + expf(10.f - s[q]));
}

// ---------------- launch ----------------

extern "C" void kernel_launch(void* const* d_in, const int* in_sizes, int n_in,
                              void* d_out, int out_size, void* d_ws, size_t ws_size,
                              hipStream_t stream) {
  const float* x   = (const float*)d_in[0];
  const int*   ei  = (const int*)d_in[1];
  const int*   ec  = (const int*)d_in[2];
  const float* Ws1 = (const float*)d_in[3];
  const float* b1  = (const float*)d_in[4];
  const float* Ws2 = (const float*)d_in[5];
  const float* b2  = (const float*)d_in[6];
  const float* Wc1 = (const float*)d_in[7];
  const float* Wc2 = (const float*)d_in[8];
  float* out = (float*)d_out;

  char* p = (char*)d_ws;
  // g2 [N,1152] bf16 (115.2MB) aliases agg1 (102.4MB) + xb (12.8MB).
  u16*  g2     = (u16*)p;
  u16*  agg1   = (u16*)p;                         // [C*N,128] bf16
  u16*  xb     = (u16*)(p + 102400000);           // [N,128] bf16
  u16*  hb     = (u16*)(p + 115200000);           // [N,256] bf16
  u16*  W1f    = (u16*)(p + 140800000);           // frag-major
  u16*  W2f    = (u16*)(p + 141389824);           // frag-major
  int2* oc     = (int2*)(p + 141979648);          // [N*C] {off,cnt}
  int*  ssrc   = (int*)(p + 145179648);           // [E]
  int*  counts = (int*)(p + 148379648);           // [N*C]
  int*  gcount = (int*)(p + 149979648);
  int*  cursor = (int*)(p + 149979904);           // [N*C]

  hipMemsetAsync(counts, 0, 1600256, stream);     // counts + gcount

  k_castx<<<25000, 256, 0, stream>>>(x, xb);
  k_wt1f<<<1152, 256, 0, stream>>>(Wc1, Ws1, W1f);
  k_wt2f<<<1152, 256, 0, stream>>>(Wc2, Ws2, W2f);

  k_hist<<<3125, 256, 0, stream>>>(ei, ec, counts);
  k_offsets<<<1563, 256, 0, stream>>>(counts, oc, cursor, gcount);
  k_fill<<<3125, 256, 0, stream>>>(ei, ec, cursor, ssrc);

  k_agg1<<<3125, 256, 0, stream>>>(xb, oc, ssrc, agg1);
  k_gemm1s<<<391, 256, 0, stream>>>(xb, agg1, W1f, b1, hb);
  k_gemm2g<<<dim3(3, 782), 256, 0, stream>>>(hb, W2f, g2);
  k_final<<<1563, 256, 0, stream>>>(g2, b2, oc, ssrc, out);
}